// Round 6
// baseline (447.051 us; speedup 1.0000x reference)
//
#include <hip/hip_runtime.h>
#include <hip/hip_bf16.h>
#include <stdint.h>
#include <math.h>

#define DIMC 2048
#define NH 16
#define HD 128
#define BBATCH 2
#define TSEQ 2048
#define MROWS (BBATCH*TSEQ)   // 4096
#define NQKV (3*DIMC)         // 6144

typedef __attribute__((ext_vector_type(8))) short short8;
typedef __attribute__((ext_vector_type(4))) float f32x4;

#define BAR() asm volatile("s_barrier" ::: "memory")

__device__ __forceinline__ short f2bf(float f) {
  union { float f; uint32_t u; } v; v.f = f;
  uint32_t r = (v.u + 0x7fffu + ((v.u >> 16) & 1u)) >> 16;
  return (short)(uint16_t)r;
}
__device__ __forceinline__ float bf2f(short s) {
  union { uint32_t u; float f; } v; v.u = ((uint32_t)(uint16_t)s) << 16;
  return v.f;
}
__device__ __forceinline__ void g2lds16(const void* g, void* l) {
  __builtin_amdgcn_global_load_lds((const __attribute__((address_space(1))) void*)g,
                                   (__attribute__((address_space(3))) void*)l, 16, 0, 0);
}

// ---------------- RoPE tables: cos/sin [T][64] ----------------
__global__ void rope_tables(float* __restrict__ cos_t, float* __restrict__ sin_t) {
  int idx = blockIdx.x * blockDim.x + threadIdx.x;   // T*64
  int t = idx >> 6, j = idx & 63;
  double inv = exp(-((double)(2 * j) / 128.0) * log(10000.0));
  float fr = (float)t * (float)inv;
  cos_t[idx] = cosf(fr);
  sin_t[idx] = sinf(fr);
}

// ---------------- fp32 -> bf16 cast (8 elems/thread) ----------------
__global__ void cast_f32_bf16(const float* __restrict__ in, short* __restrict__ out, int n8) {
  int i = blockIdx.x * blockDim.x + threadIdx.x;
  if (i >= n8) return;
  const float4* p = (const float4*)in;
  float4 a = p[2 * i], b = p[2 * i + 1];
  short8 o;
  o[0] = f2bf(a.x); o[1] = f2bf(a.y); o[2] = f2bf(a.z); o[3] = f2bf(a.w);
  o[4] = f2bf(b.x); o[5] = f2bf(b.y); o[6] = f2bf(b.z); o[7] = f2bf(b.w);
  ((short8*)out)[i] = o;
}

// ---------------- in-place RoPE on q,k [B,H,T,HD] bf16 ----------------
__global__ void rope_apply(short* __restrict__ q, short* __restrict__ k,
                           const float* __restrict__ cos_t, const float* __restrict__ sin_t) {
  int idx = blockIdx.x * blockDim.x + threadIdx.x;  // B*H*T*64
  int j = idx & 63;
  int t = (idx >> 6) & (TSEQ - 1);
  int bh = idx >> 17;
  size_t base = ((size_t)bh * TSEQ + t) * HD;
  float c = cos_t[t * 64 + j], s = sin_t[t * 64 + j];
  float x1 = bf2f(q[base + j]), x2 = bf2f(q[base + j + 64]);
  q[base + j]      = f2bf(x1 * c - x2 * s);
  q[base + j + 64] = f2bf(x2 * c + x1 * s);
  float y1 = bf2f(k[base + j]), y2 = bf2f(k[base + j + 64]);
  k[base + j]      = f2bf(y1 * c - y2 * s);
  k[base + j + 64] = f2bf(y2 * c + y1 * s);
}

// ======================= 256x128 phase-scheduled GEMM =======================
// C = A(bf16 MxK) * B(bf16 NxK)^T, BM=256 BN=128 BK=64, 512 thr (8 waves 2Mx4N).
// A double-buffered (staged 1 tile ahead), B triple-buffered (2 ahead) -> the
// per-K-tile wait is s_waitcnt vmcnt(2), never a drain. 4 phases/K-tile, each:
// {4-8 ds_read_b128, 2 global_load_lds, barrier, setprio1, 8 MFMA, setprio0}.
// LDS swizzle: chunk-XOR by row (both-sides involution, rule #21):
//   phys(row, c) = row*128B + ((c ^ (row&7))*16B),  c = k-chunk 0..7
// Staging writes linear LDS; the SOURCE chunk is pre-swizzled to compensate.
__device__ __forceinline__ void stage128(short* lds_base, const short* gsrc, int ldg, int tid) {
  #pragma unroll
  for (int j = 0; j < 2; ++j) {
    int L = j * 512 + tid;            // 16B chunk 0..1023 of a 128x64 slab
    int r = L >> 3, pc = L & 7;
    g2lds16(gsrc + (size_t)r * ldg + ((pc ^ (r & 7)) << 3), lds_base + L * 8);
  }
}
__device__ __forceinline__ short8 ldsfrag(const short* base, int row, int c) {
  return *(const short8*)(base + row * 64 + ((c ^ (row & 7)) << 3));
}

template<int EPI>
__global__ __launch_bounds__(512, 2)
void gemm256(const short* __restrict__ A, const short* __restrict__ B,
             int M, int N, int K,
             float* __restrict__ Cout,
             short* __restrict__ qp, short* __restrict__ kp, short* __restrict__ vp) {
  __shared__ short Ab[2][256 * 64];   // 64 KB
  __shared__ short Bb[3][128 * 64];   // 48 KB
  const int tid = threadIdx.x;
  const int lane = tid & 63, wave = tid >> 6;
  const int wm = wave >> 2, wn = wave & 3;
  const int bn = blockIdx.x, bm = blockIdx.y;
  const int rowA0 = bm * 256, rowB0 = bn * 128;
  const int NT = K / 64;
  const int l15 = lane & 15, l4 = lane >> 4;
  f32x4 acc[8][2] = {};

  // prologue: A(0) halves, B(0), B(1); wait A(0)+B(0), keep B(1) in flight
  stage128(&Ab[0][0],        A + (size_t)rowA0 * K,         K, tid);
  stage128(&Ab[0][128 * 64], A + (size_t)(rowA0 + 128) * K, K, tid);
  stage128(&Bb[0][0],        B + (size_t)rowB0 * K,         K, tid);
  stage128(&Bb[1][0],        B + (size_t)rowB0 * K + 64,    K, tid);
  asm volatile("s_waitcnt vmcnt(2)" ::: "memory");
  BAR();

  for (int t = 0; t < NT; ++t) {
    const short* At = Ab[t & 1];
    const short* Bt = Bb[t % 3];
    short* Anx = Ab[(t + 1) & 1];
    short* Bnx = Bb[(t + 2) % 3];
    const short* Ag = A + (size_t)rowA0 * K + (t + 1) * 64;
    const short* Bg = B + (size_t)rowB0 * K + (t + 2) * 64;
    short8 bfrag[2][2];
    #pragma unroll
    for (int ph = 0; ph < 4; ++ph) {
      short8 afrag[2][2];
      if (ph == 0) {
        #pragma unroll
        for (int n = 0; n < 2; ++n)
          #pragma unroll
          for (int ks = 0; ks < 2; ++ks)
            bfrag[n][ks] = ldsfrag(Bt, wn * 32 + n * 16 + l15, ks * 4 + l4);
      }
      #pragma unroll
      for (int m2 = 0; m2 < 2; ++m2)
        #pragma unroll
        for (int ks = 0; ks < 2; ++ks)
          afrag[m2][ks] = ldsfrag(At, wm * 128 + (ph * 2 + m2) * 16 + l15, ks * 4 + l4);
      if (ph == 0 && t + 1 < NT) stage128(Anx,            Ag,                    K, tid);
      if (ph == 1 && t + 1 < NT) stage128(Anx + 128 * 64, Ag + (size_t)128 * K,  K, tid);
      if (ph == 2 && t + 2 < NT) stage128(Bnx,            Bg,                    K, tid);
      if (ph == 3) {
        if (t + 2 < NT) asm volatile("s_waitcnt vmcnt(2)" ::: "memory");
        else            asm volatile("s_waitcnt vmcnt(0)" ::: "memory");
      }
      BAR();
      __builtin_amdgcn_s_setprio(1);
      #pragma unroll
      for (int m2 = 0; m2 < 2; ++m2)
        #pragma unroll
        for (int n = 0; n < 2; ++n)
          #pragma unroll
          for (int ks = 0; ks < 2; ++ks)
            acc[ph * 2 + m2][n] =
                __builtin_amdgcn_mfma_f32_16x16x32_bf16(afrag[m2][ks], bfrag[n][ks],
                                                        acc[ph * 2 + m2][n], 0, 0, 0);
      __builtin_amdgcn_s_setprio(0);
    }
  }

  if (EPI == 1) {
    #pragma unroll
    for (int m = 0; m < 8; ++m)
      #pragma unroll
      for (int n = 0; n < 2; ++n)
        #pragma unroll
        for (int i = 0; i < 4; ++i) {
          int gm = rowA0 + wm * 128 + m * 16 + (l4 << 2) + i;
          int gn = rowB0 + wn * 32 + n * 16 + l15;
          Cout[(size_t)gm * N + gn] = acc[m][n][i];
        }
  } else {
    short* dst = (bn < 16) ? qp : (bn < 32) ? kp : vp;
    int h = bn & 15;
    #pragma unroll
    for (int m = 0; m < 8; ++m)
      #pragma unroll
      for (int n = 0; n < 2; ++n)
        #pragma unroll
        for (int i = 0; i < 4; ++i) {
          int gm = rowA0 + wm * 128 + m * 16 + (l4 << 2) + i;
          int b = gm >> 11, tt = gm & 2047;
          int d = wn * 32 + n * 16 + l15;
          dst[(((size_t)b * NH + h) * TSEQ + tt) * HD + d] = f2bf(acc[m][n][i]);
        }
  }
}

// ---------------- flash attention (causal), QBLK=64, KVBLK=64 ----------------
// LDS swizzles (all bijective chunk-XOR within rows; rule #21 both-sides):
//  Ks : phys(row,k)  = row*128 + ((k>>3 ^ (row&7))<<3) + (k&7)     [staged via pre-swizzled g2lds src]
//  Vt : phys(d,kv)   = d*64 + ((kv>>3 ^ (d&7) ^ ((d>>3)&7))<<3) + (kv&7)
//  Pl : phys(q,kv)   = q*64 + ((kv>>3 ^ (q&7))<<3) + (kv&7)
__global__ __launch_bounds__(256)
void flash_attn(const short* __restrict__ Q, const short* __restrict__ K,
                const short* __restrict__ V, short* __restrict__ Oout) {
  __shared__ short Ks[64 * 128];     // 16KB
  __shared__ short Vt[128 * 64];     // 16KB transposed V, swizzled
  __shared__ short Pl[4 * 16 * 64];  // 8KB per-wave P, swizzled
  int tid = threadIdx.x, lane = tid & 63, wave = tid >> 6;
  // heavy-first dispatch: qt descending across bid; same (b,h) sticks to one XCD
  int bid = blockIdx.x;
  int qt = (TSEQ / 64 - 1) - (bid >> 5);
  int hb = bid & 31;
  int h = hb & 15, b = hb >> 4;
  size_t bh_off = ((size_t)b * NH + h) * TSEQ * HD;
  const short* Qp = Q + bh_off;
  const short* Kp = K + bh_off;
  const short* Vp = V + bh_off;
  int q0 = qt * 64 + wave * 16;
  short8 qf[4];
  #pragma unroll
  for (int ks = 0; ks < 4; ++ks)
    qf[ks] = *(const short8*)(Qp + (size_t)(q0 + (lane & 15)) * HD + ks * 32 + 8 * (lane >> 4));
  float m_run[4], l_run[4];
  f32x4 acc_o[8] = {};
  #pragma unroll
  for (int i = 0; i < 4; ++i) { m_run[i] = -INFINITY; l_run[i] = 0.f; }
  const float scale = 0.08838834764831845f;  // 1/sqrt(128)
  for (int it = 0; it <= qt; ++it) {
    int kv0 = it * 64;
    // V tile -> regs (issue first; latency hides under K staging)
    short8 vv[4];
    #pragma unroll
    for (int j = 0; j < 4; ++j) {
      int e = tid + j * 256;
      int r = e >> 4, c0 = (e & 15) * 8;
      vv[j] = *(const short8*)(Vp + (size_t)(kv0 + r) * HD + c0);
    }
    // stage K (64x128), pre-swizzled source chunk so swizzled read is linear-dest-safe
    #pragma unroll
    for (int j = 0; j < 4; ++j) {
      int c = tid + j * 256;          // physical 16B chunk index
      int r = c >> 4, cc = c & 15;
      g2lds16(Kp + (size_t)(kv0 + r) * HD + ((cc ^ (r & 7)) << 3), Ks + c * 8);
    }
    // scatter V transpose into swizzled Vt
    #pragma unroll
    for (int j = 0; j < 4; ++j) {
      int e = tid + j * 256;
      int r = e >> 4, c0 = (e & 15) * 8;
      int rc = r >> 3, rl = r & 7;
      #pragma unroll
      for (int jj = 0; jj < 8; ++jj) {
        int d = c0 + jj;
        int pch = rc ^ (d & 7) ^ ((d >> 3) & 7);
        Vt[d * 64 + (pch << 3) + rl] = vv[j][jj];
      }
    }
    __syncthreads();
    // S = Q K^T  (16 q-rows x 64 kv)
    f32x4 sa[4] = {};
    __builtin_amdgcn_s_setprio(1);
    #pragma unroll
    for (int nf = 0; nf < 4; ++nf)
      #pragma unroll
      for (int ks = 0; ks < 4; ++ks) {
        int row = nf * 16 + (lane & 15);
        int lch = ks * 4 + (lane >> 4);
        short8 kf = *(const short8*)(Ks + row * 128 + ((lch ^ (row & 7)) << 3));
        sa[nf] = __builtin_amdgcn_mfma_f32_16x16x32_bf16(qf[ks], kf, sa[nf], 0, 0, 0);
      }
    __builtin_amdgcn_s_setprio(0);
    bool lastTile = (it == qt);
    #pragma unroll
    for (int nf = 0; nf < 4; ++nf)
      #pragma unroll
      for (int i = 0; i < 4; ++i) {
        float s = sa[nf][i] * scale;
        if (lastTile) {
          int kvc = kv0 + nf * 16 + (lane & 15);
          int qr = q0 + ((lane >> 4) << 2) + i;
          if (kvc > qr) s = -INFINITY;
        }
        sa[nf][i] = s;
      }
    // online softmax per q-row (rows live across 16 lanes)
    #pragma unroll
    for (int i = 0; i < 4; ++i) {
      float t = fmaxf(fmaxf(sa[0][i], sa[1][i]), fmaxf(sa[2][i], sa[3][i]));
      t = fmaxf(t, __shfl_xor(t, 1));
      t = fmaxf(t, __shfl_xor(t, 2));
      t = fmaxf(t, __shfl_xor(t, 4));
      t = fmaxf(t, __shfl_xor(t, 8));
      float mn = fmaxf(m_run[i], t);
      float al = __expf(m_run[i] - mn);
      m_run[i] = mn;
      float su = 0.f;
      #pragma unroll
      for (int nf = 0; nf < 4; ++nf) {
        float p = __expf(sa[nf][i] - mn);
        sa[nf][i] = p;
        su += p;
      }
      su += __shfl_xor(su, 1);
      su += __shfl_xor(su, 2);
      su += __shfl_xor(su, 4);
      su += __shfl_xor(su, 8);
      l_run[i] = l_run[i] * al + su;
      #pragma unroll
      for (int nfd = 0; nfd < 8; ++nfd) acc_o[nfd][i] *= al;
    }
    // P -> LDS (per wave, swizzled)
    short* Pw = Pl + wave * 16 * 64;
    #pragma unroll
    for (int nf = 0; nf < 4; ++nf)
      #pragma unroll
      for (int i = 0; i < 4; ++i) {
        int qq = ((lane >> 4) << 2) + i;
        int kv = nf * 16 + (lane & 15);
        Pw[qq * 64 + (((kv >> 3) ^ (qq & 7)) << 3) + (kv & 7)] = f2bf(sa[nf][i]);
      }
    // O += P V
    __builtin_amdgcn_s_setprio(1);
    #pragma unroll
    for (int ks2 = 0; ks2 < 2; ++ks2) {
      int qq = lane & 15;
      int lchp = ks2 * 4 + (lane >> 4);
      short8 pf = *(const short8*)(Pw + qq * 64 + ((lchp ^ (qq & 7)) << 3));
      #pragma unroll
      for (int nfd = 0; nfd < 8; ++nfd) {
        int d = nfd * 16 + (lane & 15);
        int lch = ks2 * 4 + (lane >> 4);
        int pch = lch ^ (d & 7) ^ ((d >> 3) & 7);
        short8 vf = *(const short8*)(Vt + d * 64 + (pch << 3));
        acc_o[nfd] = __builtin_amdgcn_mfma_f32_16x16x32_bf16(pf, vf, acc_o[nfd], 0, 0, 0);
      }
    }
    __builtin_amdgcn_s_setprio(0);
    __syncthreads();
  }
  // epilogue: O /= l, write bf16 to attn_out [B,T,DIM]
  #pragma unroll
  for (int nfd = 0; nfd < 8; ++nfd)
    #pragma unroll
    for (int i = 0; i < 4; ++i) {
      int qr = q0 + ((lane >> 4) << 2) + i;
      int col = h * HD + nfd * 16 + (lane & 15);
      Oout[((size_t)b * TSEQ + qr) * DIMC + col] = f2bf(acc_o[nfd][i] / l_run[i]);
    }
}

extern "C" void kernel_launch(void* const* d_in, const int* in_sizes, int n_in,
                              void* d_out, int out_size, void* d_ws, size_t ws_size,
                              hipStream_t stream) {
  const float* x     = (const float*)d_in[0];
  const float* w_qkv = (const float*)d_in[1];
  const float* w_out = (const float*)d_in[2];
  float* out = (float*)d_out;
  char* ws = (char*)d_ws;
  size_t off = 0;
  auto alloc = [&](size_t bytes) {
    void* p = ws + off;
    off += (bytes + 255) & ~(size_t)255;
    return p;
  };
  float* cos_t = (float*)alloc((size_t)TSEQ * 64 * 4);
  float* sin_t = (float*)alloc((size_t)TSEQ * 64 * 4);
  short* xb    = (short*)alloc((size_t)MROWS * DIMC * 2);
  short* wqkvb = (short*)alloc((size_t)NQKV * DIMC * 2);
  short* woutb = (short*)alloc((size_t)DIMC * DIMC * 2);
  short* q     = (short*)alloc((size_t)BBATCH * NH * TSEQ * HD * 2);
  short* k     = (short*)alloc((size_t)BBATCH * NH * TSEQ * HD * 2);
  short* v     = (short*)alloc((size_t)BBATCH * NH * TSEQ * HD * 2);
  short* attn  = (short*)alloc((size_t)MROWS * DIMC * 2);

  rope_tables<<<(TSEQ * 64) / 256, 256, 0, stream>>>(cos_t, sin_t);
  cast_f32_bf16<<<(MROWS * DIMC / 8 + 255) / 256, 256, 0, stream>>>(x, xb, MROWS * DIMC / 8);
  cast_f32_bf16<<<(NQKV * DIMC / 8 + 255) / 256, 256, 0, stream>>>(w_qkv, wqkvb, NQKV * DIMC / 8);
  cast_f32_bf16<<<(DIMC * DIMC / 8 + 255) / 256, 256, 0, stream>>>(w_out, woutb, DIMC * DIMC / 8);

  gemm256<0><<<dim3(NQKV / 128, MROWS / 256), 512, 0, stream>>>(
      xb, wqkvb, MROWS, NQKV, DIMC, nullptr, q, k, v);

  rope_apply<<<(BBATCH * NH * TSEQ * 64) / 256, 256, 0, stream>>>(q, k, cos_t, sin_t);

  flash_attn<<<dim3((TSEQ / 64) * NH * BBATCH), 256, 0, stream>>>(q, k, v, attn);

  gemm256<1><<<dim3(DIMC / 128, MROWS / 256), 512, 0, stream>>>(
      attn, woutb, MROWS, DIMC, DIMC, out, nullptr, nullptr, nullptr);
}